// Round 1
// 177.011 us; speedup vs baseline: 1.4619x; 1.4619x over previous
//
#include <hip/hip_runtime.h>

// ---------------------------------------------------------------------------
// MHLP predictor — f16 MFMA, occupancy round.
// R17 (259 us) was latency-bound at 4 waves/CU (k_attn): 37.4 KB of its
// 63.5 KB LDS was *shared weight frags*. This round reads all B-frags
// directly from d_ws global (L1/L2-resident, ~14 TB/s needed << 34.5 L2
// ceiling) and keeps only per-wave scratch in LDS:
//   k_attn: 25.7 KB/block -> 6 blk/CU = 12 waves/CU (was 4)
//   k_enc :  9.2 KB/block -> VGPR-capped ~16 waves/CU (was 8)
//   k_pre : grid-stride over 64 blocks (was 1 serial block)
// No weight staging -> no __syncthreads anywhere; 8192 blocks x 1 tile/wave.
// Frag layouts unchanged (m89/m91/m120-verified):
//   A[m=lane&15][k=(lane>>4)*8+j]; B-frag[lane][j]=W[nt*16+(lane&15)]
//   [ks*32+(lane>>4)*8+j]; C/D: col=lane&15, row=(lane>>4)*4+reg.
// Predict: k_attn 99 -> ~45 us (Occ 10.7->~33%, VALUBusy 31->~70%),
// k_enc -> ~50 us, total 259 -> ~105-135 us; absmax unchanged ~1e-3.
// ---------------------------------------------------------------------------

using s8v = __attribute__((ext_vector_type(8))) short;
using h8  = __attribute__((ext_vector_type(8))) _Float16;
using f4  = __attribute__((ext_vector_type(4))) float;

#define BTOT 262144

// d_ws u16-unit layout (pre-swizzled f16 weight frags + arch)
#define WF_W1   0        // 12288  (K=75->KS=3, NT=8)
#define WF_W2   12288    // 8192   (K=128->KS=4, NT=4)
#define WF_IP   20480    // 12288  (K=64->KS=2, NT=12)
#define WF_OP   32768    // 4096   (K=64->KS=2, NT=4)
#define WF_W3   36864    // 2048   (K=64->KS=2, NT=2)
#define WF_HWE  38912    // 256    (hw_embed f16 [4][64])
#define WF_ARCH 65536    // BTOT*64 arch f16

__device__ __forceinline__ unsigned short f2h(float f) {
  _Float16 h = (_Float16)f;
  return __builtin_bit_cast(unsigned short, h);
}
__device__ __forceinline__ float h2f(unsigned short u) {
  return (float)__builtin_bit_cast(_Float16, u);
}

__device__ __forceinline__ void swz(const float* __restrict__ W,
                                    unsigned short* __restrict__ dst,
                                    int Kreal, int KS, int NT, int t, int stride) {
  const int total = KS * NT * 512;
  for (int i = t; i < total; i += stride) {
    const int j = i & 7, ln = (i >> 3) & 63, fr = i >> 9;
    const int nt = fr % NT, ks = fr / NT;
    const int n = nt * 16 + (ln & 15);
    const int k = ks * 32 + (ln >> 4) * 8 + j;
    dst[i] = (k < Kreal) ? f2h(W[n * Kreal + k]) : (unsigned short)0;
  }
}

__global__ void k_pre(const float* __restrict__ hwe,
                      const float* __restrict__ W1, const float* __restrict__ W2,
                      const float* __restrict__ ipw, const float* __restrict__ opw,
                      const float* __restrict__ W3,
                      unsigned short* __restrict__ ws) {
  const int t = blockIdx.x * 256 + threadIdx.x;
  const int stride = gridDim.x * 256;
  swz(W1,  ws + WF_W1, 75, 3, 8, t, stride);
  swz(W2,  ws + WF_W2, 128, 4, 4, t, stride);
  swz(ipw, ws + WF_IP, 64, 2, 12, t, stride);
  swz(opw, ws + WF_OP, 64, 2, 4, t, stride);
  swz(W3,  ws + WF_W3, 64, 2, 2, t, stride);
  for (int i = t; i < 256; i += stride) ws[WF_HWE + i] = f2h(hwe[i]);
}

// ===================== K1: encoder -> arch[B][64] f16 ======================
// LDS u16 per wave (2304): h [16][136]@0 (arch [16][72] reuses front),
//   targ [16][8]@2176.  Block = 2 waves -> 4608 u16 = 9216 B.
// Weight frags (W1, W2) read straight from d_ws (L1/L2-resident).
__global__ __launch_bounds__(128, 3) void k_enc(
    const int* __restrict__ g_op, const int* __restrict__ g_wd,
    const float* __restrict__ g_b1, const float* __restrict__ g_b2,
    const float* __restrict__ g_ln1g, const float* __restrict__ g_ln1b,
    const unsigned short* __restrict__ wsf, unsigned short* __restrict__ g_arch) {
  __shared__ __align__(16) unsigned short sm[4608];
  const int tid = threadIdx.x;
  const int wave = tid >> 6, lane = tid & 63;
  const int quad = lane >> 4, l15 = lane & 15;
  unsigned short* pw = sm + wave * 2304;
  const int m0 = (blockIdx.x * 2 + wave) * 16;    // 8192 blocks x 2 waves

  if (lane < 16) {
    const int smp = m0 + lane;
#pragma unroll
    for (int l = 0; l < 5; ++l) {
      const int c = 15 * l + g_op[smp * 5 + l] * 3 + g_wd[smp * 5 + l];
      pw[2176 + lane * 8 + l] = (unsigned short)c;
    }
    pw[2176 + lane * 8 + 5] = 0xFFFFu;
    pw[2176 + lane * 8 + 6] = 0xFFFFu;
    pw[2176 + lane * 8 + 7] = 0xFFFFu;
  }
  const s8v trow = *(const s8v*)(pw + 2176 + l15 * 8);

  h8 aoh[3];
#pragma unroll
  for (int ks = 0; ks < 3; ++ks) {
    s8v a;
#pragma unroll
    for (int j = 0; j < 8; ++j) {
      const int k = ks * 32 + quad * 8 + j;
      bool hit = false;
#pragma unroll
      for (int l = 0; l < 5; ++l)
        hit = hit || (k == (int)(unsigned short)trow[l]);
      a[j] = hit ? (short)0x3C00 : (short)0;   // f16 1.0
    }
    aoh[ks] = __builtin_bit_cast(h8, a);
  }

  // S1: h = relu(onehot @ W1^T + b1) -> pw[0..2176] stride 136 (f16)
#pragma unroll
  for (int nt = 0; nt < 8; ++nt) {
    f4 acc = {0.f, 0.f, 0.f, 0.f};
#pragma unroll
    for (int ks = 0; ks < 3; ++ks) {
      const h8 bf = *(const h8*)(wsf + WF_W1 + ((ks * 8 + nt) * 64 + lane) * 8);
      acc = __builtin_amdgcn_mfma_f32_16x16x32_f16(aoh[ks], bf, acc, 0, 0, 0);
    }
    const int col = nt * 16 + l15;
    const float bias = g_b1[col];
#pragma unroll
    for (int r = 0; r < 4; ++r) {
      float v = acc[r] + bias;
      v = v > 0.f ? v : 0.f;
      pw[(quad * 4 + r) * 136 + col] = f2h(v);
    }
  }

  // S2: arch = LN1(h @ W2^T + b2) -> pw[0..1152] stride 72
  h8 a2[4];
#pragma unroll
  for (int ks = 0; ks < 4; ++ks)
    a2[ks] = *(const h8*)(pw + l15 * 136 + ks * 32 + quad * 8);
  f4 acc2[4];
#pragma unroll
  for (int nt = 0; nt < 4; ++nt) {
    f4 acc = {0.f, 0.f, 0.f, 0.f};
#pragma unroll
    for (int ks = 0; ks < 4; ++ks) {
      const h8 bf = *(const h8*)(wsf + WF_W2 + ((ks * 4 + nt) * 64 + lane) * 8);
      acc = __builtin_amdgcn_mfma_f32_16x16x32_f16(a2[ks], bf, acc, 0, 0, 0);
    }
    acc2[nt] = acc;
  }
  {
    float val[4][4];
#pragma unroll
    for (int nt = 0; nt < 4; ++nt) {
      const float bias = g_b2[nt * 16 + l15];
#pragma unroll
      for (int r = 0; r < 4; ++r) val[nt][r] = acc2[nt][r] + bias;
    }
#pragma unroll
    for (int r = 0; r < 4; ++r) {
      float s = val[0][r] + val[1][r] + val[2][r] + val[3][r];
      float q = val[0][r] * val[0][r] + val[1][r] * val[1][r] +
                val[2][r] * val[2][r] + val[3][r] * val[3][r];
#pragma unroll
      for (int off = 1; off <= 8; off <<= 1) {
        s += __shfl_xor(s, off);
        q += __shfl_xor(q, off);
      }
      const float mean = s * (1.f / 64.f);
      const float var  = q * (1.f / 64.f) - mean * mean;
      const float rstd = rsqrtf(var + 1e-5f);
#pragma unroll
      for (int nt = 0; nt < 4; ++nt) {
        const int col = nt * 16 + l15;
        const float gg = g_ln1g[col], bb = g_ln1b[col];
        pw[(quad * 4 + r) * 72 + col] = f2h((val[nt][r] - mean) * rstd * gg + bb);
      }
    }
  }

  // cooperative store arch tile [16][64] f16 -> g_arch
#pragma unroll
  for (int o = 0; o < 2; ++o) {
    const int c = o * 64 + lane;
    const int row = c >> 3, coloff = (c & 7) * 8;
    const s8v v = *(const s8v*)(pw + row * 72 + coloff);
    *(s8v*)(g_arch + (size_t)(m0 + row) * 64 + coloff) = v;
  }
}

// ===================== K2: attention + head -> out =========================
// LDS u16 per wave (6432): qkv [32][200]@0; ctx [32][72]@0 overlay;
//   pooled [16][72]@2304; archt [16][72]@3456; hwi@6400(16).
// Block = 2 waves -> 12864 u16 = 25728 B -> 6 blocks/CU = 12 waves/CU.
// All weight frags (IP, OP, W3, HWE) read straight from d_ws.
__global__ __launch_bounds__(128, 3) void k_attn(
    const int* __restrict__ g_hw,
    const float* __restrict__ g_hwe,
    const float* __restrict__ g_ipb, const float* __restrict__ g_opb,
    const float* __restrict__ g_ln2g, const float* __restrict__ g_ln2b,
    const float* __restrict__ g_b3,  const float* __restrict__ g_W4,
    const float* __restrict__ g_b4,
    const unsigned short* __restrict__ wsf,   // d_ws base (u16)
    float* __restrict__ g_out) {
  __shared__ __align__(16) unsigned short sm[12864];
  const int tid = threadIdx.x;
  const unsigned short* g_arch = wsf + WF_ARCH;
  const int wave = tid >> 6, lane = tid & 63;
  const int quad = lane >> 4, l15 = lane & 15;
  unsigned short* pw = sm + wave * 6432;
  const int m0 = (blockIdx.x * 2 + wave) * 16;    // 8192 blocks x 2 waves

  if (lane < 16) pw[6400 + lane] = (unsigned short)g_hw[m0 + lane];

  // S3: qkv = [hw_emb; arch] @ in_proj^T + ipb -> qkv[32][200] f16
  const int hwrow = (int)pw[6400 + l15];
  h8 at0[2], at1[2];
#pragma unroll
  for (int ks = 0; ks < 2; ++ks) {
    at0[ks] = *(const h8*)(wsf + WF_HWE + hwrow * 64 + ks * 32 + quad * 8);
    at1[ks] = *(const h8*)(g_arch + (size_t)(m0 + l15) * 64 + ks * 32 + quad * 8);
  }
#pragma unroll
  for (int nt = 0; nt < 12; ++nt) {
    const h8 bf0 = *(const h8*)(wsf + WF_IP + ((0 * 12 + nt) * 64 + lane) * 8);
    const h8 bf1 = *(const h8*)(wsf + WF_IP + ((1 * 12 + nt) * 64 + lane) * 8);
    f4 a0 = {0.f, 0.f, 0.f, 0.f}, a1 = {0.f, 0.f, 0.f, 0.f};
    a0 = __builtin_amdgcn_mfma_f32_16x16x32_f16(at0[0], bf0, a0, 0, 0, 0);
    a0 = __builtin_amdgcn_mfma_f32_16x16x32_f16(at0[1], bf1, a0, 0, 0, 0);
    a1 = __builtin_amdgcn_mfma_f32_16x16x32_f16(at1[0], bf0, a1, 0, 0, 0);
    a1 = __builtin_amdgcn_mfma_f32_16x16x32_f16(at1[1], bf1, a1, 0, 0, 0);
    const int col = nt * 16 + l15;
    const float bias = g_ipb[col];
#pragma unroll
    for (int r = 0; r < 4; ++r) {
      pw[(quad * 4 + r) * 200 + col]      = f2h(a0[r] + bias);
      pw[(16 + quad * 4 + r) * 200 + col] = f2h(a1[r] + bias);
    }
  }

  // S4: attention per (sample=l15, head=quad)
  float ctx[2][16];
  {
    float qv[2][16], kv[2][16], vv[2][16];
#pragma unroll
    for (int tt = 0; tt < 2; ++tt) {
      const unsigned short* base = pw + (tt * 16 + l15) * 200;
#pragma unroll
      for (int c = 0; c < 2; ++c) {
        const h8 qq = *(const h8*)(base + quad * 16 + c * 8);
        const h8 kk = *(const h8*)(base + 64 + quad * 16 + c * 8);
        const h8 vvv = *(const h8*)(base + 128 + quad * 16 + c * 8);
#pragma unroll
        for (int d = 0; d < 8; ++d) {
          qv[tt][c * 8 + d] = (float)qq[d];
          kv[tt][c * 8 + d] = (float)kk[d];
          vv[tt][c * 8 + d] = (float)vvv[d];
        }
      }
    }
    float s00 = 0.f, s01 = 0.f, s10 = 0.f, s11 = 0.f;
#pragma unroll
    for (int d = 0; d < 16; ++d) {
      s00 += qv[0][d] * kv[0][d];
      s01 += qv[0][d] * kv[1][d];
      s10 += qv[1][d] * kv[0][d];
      s11 += qv[1][d] * kv[1][d];
    }
    s00 *= 0.25f; s01 *= 0.25f; s10 *= 0.25f; s11 *= 0.25f;
    const float mA = fmaxf(s00, s01);
    const float e0 = __expf(s00 - mA), e1 = __expf(s01 - mA);
    const float iA = 1.f / (e0 + e1);
    const float a00 = e0 * iA, a01 = e1 * iA;
    const float mB = fmaxf(s10, s11);
    const float f0 = __expf(s10 - mB), f1 = __expf(s11 - mB);
    const float iB = 1.f / (f0 + f1);
    const float a10 = f0 * iB, a11 = f1 * iB;
#pragma unroll
    for (int d = 0; d < 16; ++d) {
      ctx[0][d] = a00 * vv[0][d] + a01 * vv[1][d];
      ctx[1][d] = a10 * vv[0][d] + a11 * vv[1][d];
    }
  }
#pragma unroll
  for (int tt = 0; tt < 2; ++tt)
#pragma unroll
    for (int d = 0; d < 16; d += 2) {
      const unsigned pk = (unsigned)f2h(ctx[tt][d]) |
                          ((unsigned)f2h(ctx[tt][d + 1]) << 16);
      *(unsigned*)(pw + (tt * 16 + l15) * 72 + quad * 16 + d) = pk;
    }

  // stage arch tile (residual) -> archt@3456 (qkv rows dead)
#pragma unroll
  for (int o = 0; o < 2; ++o) {
    const int c = o * 64 + lane;
    const int row = c >> 3, coloff = (c & 7) * 8;
    const s8v v = *(const s8v*)(g_arch + (size_t)(m0 + row) * 64 + coloff);
    *(s8v*)(pw + 3456 + row * 72 + coloff) = v;
  }

  // S5: out_proj + residual + LN2 + mean-pool -> pooled[16][72]@2304
  h8 ca[2][2];
#pragma unroll
  for (int mt = 0; mt < 2; ++mt)
#pragma unroll
    for (int ks = 0; ks < 2; ++ks)
      ca[mt][ks] = *(const h8*)(pw + (mt * 16 + l15) * 72 + ks * 32 + quad * 8);
  f4 oacc[2][4];
#pragma unroll
  for (int nt = 0; nt < 4; ++nt) {
    const h8 bf0 = *(const h8*)(wsf + WF_OP + ((0 * 4 + nt) * 64 + lane) * 8);
    const h8 bf1 = *(const h8*)(wsf + WF_OP + ((1 * 4 + nt) * 64 + lane) * 8);
#pragma unroll
    for (int mt = 0; mt < 2; ++mt) {
      f4 acc = {0.f, 0.f, 0.f, 0.f};
      acc = __builtin_amdgcn_mfma_f32_16x16x32_f16(ca[mt][0], bf0, acc, 0, 0, 0);
      acc = __builtin_amdgcn_mfma_f32_16x16x32_f16(ca[mt][1], bf1, acc, 0, 0, 0);
      oacc[mt][nt] = acc;
    }
  }
  float pool[4][4];
#pragma unroll
  for (int mt = 0; mt < 2; ++mt) {
    float val[4][4];
#pragma unroll
    for (int nt = 0; nt < 4; ++nt) {
      const int col = nt * 16 + l15;
      const float bias = g_opb[col];
#pragma unroll
      for (int r = 0; r < 4; ++r) {
        const int row = quad * 4 + r;
        float res;
        if (mt == 0) {
          const int hr = (int)pw[6400 + row];
          res = g_hwe[hr * 64 + col];
        } else {
          res = h2f(pw[3456 + row * 72 + col]);
        }
        val[nt][r] = oacc[mt][nt][r] + bias + res;
      }
    }
#pragma unroll
    for (int r = 0; r < 4; ++r) {
      float s = val[0][r] + val[1][r] + val[2][r] + val[3][r];
      float q = val[0][r] * val[0][r] + val[1][r] * val[1][r] +
                val[2][r] * val[2][r] + val[3][r] * val[3][r];
#pragma unroll
      for (int off = 1; off <= 8; off <<= 1) {
        s += __shfl_xor(s, off);
        q += __shfl_xor(q, off);
      }
      const float mean = s * (1.f / 64.f);
      const float var  = q * (1.f / 64.f) - mean * mean;
      const float rstd = rsqrtf(var + 1e-5f);
#pragma unroll
      for (int nt = 0; nt < 4; ++nt) {
        const int col = nt * 16 + l15;
        const float gg = g_ln2g[col], bb = g_ln2b[col];
        const float xn = (val[nt][r] - mean) * rstd * gg + bb;
        if (mt == 0) pool[nt][r] = 0.5f * xn;
        else         pool[nt][r] += 0.5f * xn;
      }
    }
  }
#pragma unroll
  for (int nt = 0; nt < 4; ++nt)
#pragma unroll
    for (int r = 0; r < 4; ++r)
      pw[2304 + (quad * 4 + r) * 72 + nt * 16 + l15] = f2h(pool[nt][r]);

  // S6: head
  h8 pa[2];
#pragma unroll
  for (int ks = 0; ks < 2; ++ks)
    pa[ks] = *(const h8*)(pw + 2304 + l15 * 72 + ks * 32 + quad * 8);
  float part[4] = {0.f, 0.f, 0.f, 0.f};
#pragma unroll
  for (int nt = 0; nt < 2; ++nt) {
    const h8 bf0 = *(const h8*)(wsf + WF_W3 + ((0 * 2 + nt) * 64 + lane) * 8);
    const h8 bf1 = *(const h8*)(wsf + WF_W3 + ((1 * 2 + nt) * 64 + lane) * 8);
    f4 acc = {0.f, 0.f, 0.f, 0.f};
    acc = __builtin_amdgcn_mfma_f32_16x16x32_f16(pa[0], bf0, acc, 0, 0, 0);
    acc = __builtin_amdgcn_mfma_f32_16x16x32_f16(pa[1], bf1, acc, 0, 0, 0);
    const int col = nt * 16 + l15;
    const float bias = g_b3[col];
    const float w4v  = g_W4[col];
#pragma unroll
    for (int r = 0; r < 4; ++r) {
      float y = acc[r] + bias;
      y = y > 0.f ? y : 0.f;
      part[r] += y * w4v;
    }
  }
#pragma unroll
  for (int off = 1; off <= 8; off <<= 1)
#pragma unroll
    for (int r = 0; r < 4; ++r)
      part[r] += __shfl_xor(part[r], off);
  const float b4v = g_b4[0];
  if (l15 == 0) {
#pragma unroll
    for (int r = 0; r < 4; ++r)
      g_out[m0 + quad * 4 + r] = part[r] + b4v;
  }
}

extern "C" void kernel_launch(void* const* d_in, const int* in_sizes, int n_in,
                              void* d_out, int out_size, void* d_ws, size_t ws_size,
                              hipStream_t stream) {
  (void)in_sizes; (void)n_in; (void)out_size; (void)ws_size;
  unsigned short* ws = (unsigned short*)d_ws;

  k_pre<<<64, 256, 0, stream>>>(
      (const float*)d_in[3], (const float*)d_in[4], (const float*)d_in[6],
      (const float*)d_in[10], (const float*)d_in[12], (const float*)d_in[16],
      ws);

  k_enc<<<8192, 128, 0, stream>>>(
      (const int*)d_in[1], (const int*)d_in[2],
      (const float*)d_in[5], (const float*)d_in[7],
      (const float*)d_in[8], (const float*)d_in[9],
      ws, ws + WF_ARCH);

  k_attn<<<8192, 128, 0, stream>>>(
      (const int*)d_in[0],
      (const float*)d_in[3],
      (const float*)d_in[11], (const float*)d_in[13],
      (const float*)d_in[14], (const float*)d_in[15],
      (const float*)d_in[17], (const float*)d_in[18],
      (const float*)d_in[19],
      ws, (float*)d_out);
}